// Round 1
// 31078.091 us; speedup vs baseline: 1.3404x; 1.3404x over previous
//
#include <hip/hip_runtime.h>
#include <hip/hip_bf16.h>

#define TSTEPS 512
#define BATCH  128
#define DIM    512
#define HDIM   512
#define ODIM   256
#define N3     1536

// ---- ws layout (float offsets) ----
// Barrier region: 512 uints = 4 independent quadrant barriers at q*128
// (per quadrant: 8 group counters 32B apart at 0..56, root at 64, epoch at 72)
#define OFF_BAR  0
#define OFF_XT   512       // xT  [256][128]
#define OFF_ST   33280     // sT  [512][128]
#define OFF_ZT   98816     // zT  [512][128]
#define OFF_RST  164352    // rsT [512][128]
#define OFF_PST  229888    // psT [512][128]
#define OFF_SUT  295424    // suT [1024][128]
#define OFF_WT   426496    // Wt   [1536][256]
#define OFF_UT1  819712    // Ut1  [1024][512]
#define OFF_UST  1344000   // Ust  [512][512]
#define OFF_WXOT 1606144   // Wxot [256][512]
#define OFF_HV   1737216   // bf16 [512][1536][128]

__device__ __forceinline__ float sigmoid_(float a) {
  return 1.0f / (1.0f + __expf(-a));
}
__device__ __forceinline__ float tanh_(float a) {
  a = fminf(fmaxf(a, -30.0f), 30.0f);
  float e = __expf(2.0f * a);
  return (e - 1.0f) / (e + 1.0f);
}

// LLC-coherent state accessors (sc1 encoding, bypass incoherent per-XCD L2,
// NO fence instructions — weights stay cached in L1/L2).
__device__ __forceinline__ float ld(const float* p) {
  return __hip_atomic_load((float*)p, __ATOMIC_RELAXED, __HIP_MEMORY_SCOPE_AGENT);
}
__device__ __forceinline__ void st(float* p, float v) {
  __hip_atomic_store(p, v, __ATOMIC_RELAXED, __HIP_MEMORY_SCOPE_AGENT);
}

// ---- one-time weight transposes into ws ----
__global__ void prep_kernel(const float* __restrict__ W, const float* __restrict__ U,
                            const float* __restrict__ Wx, float* __restrict__ ws) {
  int i = blockIdx.x * 256 + threadIdx.x;
  if (i < 393216) {                       // Wt[c][k] = W[k][c]
    int c = i >> 8, k = i & 255;
    ws[OFF_WT + i] = W[(size_t)k * N3 + c];
  } else if (i < 917504) {                // Ut1[c][k] = U[k][c], c<1024
    int j = i - 393216; int c = j >> 9, k = j & 511;
    ws[OFF_UT1 + j] = U[(size_t)k * N3 + c];
  } else if (i < 1179648) {               // Ust[c][k] = U[k][1024+c]
    int j = i - 917504; int c = j >> 9, k = j & 511;
    ws[OFF_UST + j] = U[(size_t)k * N3 + 1024 + c];
  } else if (i < 1310720) {               // Wxot[c][k] = W_x[k][c], c<256
    int j = i - 1179648; int c = j >> 9, k = j & 511;
    ws[OFF_WXOT + j] = Wx[(size_t)k * 768 + c];
  }
}

// ---- state init ----
__global__ void init_kernel(const float* __restrict__ H, float* __restrict__ ws) {
  int i = blockIdx.x * 256 + threadIdx.x;   // grid 512 -> 131072
  if (i < 512) ((unsigned*)ws)[OFF_BAR + i] = 0u;
  if (i < 65536) ws[OFF_ST + i] = 0.0f;
  if (i < 131072) ws[OFF_SUT + i] = 0.0f;
  if (i < 32768) {
    int c = i >> 7, b = i & 127;
    const float* hrow = H + ((size_t)b * TSTEPS + (TSTEPS - 1)) * DIM;
    ws[OFF_XT + i] = hrow[c] + hrow[c + ODIM];
  }
}

// ---- hv precompute, transposed bf16 store: hvT[t][c][b] ----
__global__ void hv_kernel(const float* __restrict__ H,
                          const float* __restrict__ Vr,
                          const float* __restrict__ Vz,
                          const float* __restrict__ Vs,
                          __hip_bfloat16* __restrict__ hvT) {
  __shared__ float tile[64 * 33];
  int c  = threadIdx.x & 63;
  int q  = threadIdx.x >> 6;
  int i0 = blockIdx.x * 32;
  int l  = i0 >> 7;
  int b0 = i0 & 127;
  int n0 = blockIdx.y * 64;
  int seg = n0 >> 9;
  int jj  = (n0 & 511) + c;
  const float* V = (seg == 0) ? Vr : ((seg == 1) ? Vz : Vs);

  const float* Arow[8];
  #pragma unroll
  for (int rr = 0; rr < 8; ++rr) {
    int b = b0 + q + rr * 4;
    Arow[rr] = H + ((size_t)b * TSTEPS + (TSTEPS - 1 - l)) * DIM;
  }
  float acc[8];
  #pragma unroll
  for (int rr = 0; rr < 8; ++rr) acc[rr] = 0.0f;

  for (int k = 0; k < DIM; k += 4) {
    float v0 = V[(size_t)(k + 0) * HDIM + jj];
    float v1 = V[(size_t)(k + 1) * HDIM + jj];
    float v2 = V[(size_t)(k + 2) * HDIM + jj];
    float v3 = V[(size_t)(k + 3) * HDIM + jj];
    #pragma unroll
    for (int rr = 0; rr < 8; ++rr) {
      float4 a = *(const float4*)(Arow[rr] + k);
      acc[rr] = fmaf(a.x, v0, acc[rr]);
      acc[rr] = fmaf(a.y, v1, acc[rr]);
      acc[rr] = fmaf(a.z, v2, acc[rr]);
      acc[rr] = fmaf(a.w, v3, acc[rr]);
    }
  }
  #pragma unroll
  for (int rr = 0; rr < 8; ++rr) tile[c * 33 + q + 4 * rr] = acc[rr];
  __syncthreads();
  #pragma unroll
  for (int i = 0; i < 8; ++i) {
    int lin = i * 256 + threadIdx.x;
    int cc = lin >> 5, bb = lin & 31;
    hvT[((size_t)l * N3 + n0 + cc) * 128 + b0 + bb] = __float2bfloat16(tile[cc * 33 + bb]);
  }
}

// ---- cooperative LDS staging of a [ROWS][32] column slice of state[k*128 + r0 + j]
// Linear layout smem[k*32+j]: staging writes (lanes share k, differ j) and
// compute reads (lanes share k, differ j) are both bank-conflict-free.
// 16-wide independent sc1 load batches -> one LLC latency per 16, not per load.
template<int ELEMS>
__device__ __forceinline__ void stage_cols(const float* __restrict__ src, int r0,
                                           int tid, float* smem) {
  #pragma unroll
  for (int base = 0; base < ELEMS; base += 4096) {
    float v[16];
    #pragma unroll
    for (int u = 0; u < 16; ++u) {
      int lin = base + u * 256 + tid;
      v[u] = ld(src + ((lin >> 5) << 7) + r0 + (lin & 31));
    }
    #pragma unroll
    for (int u = 0; u < 16; ++u) {
      smem[base + u * 256 + tid] = v[u];
    }
  }
}

// ---- fence-free quadrant barrier: 64 blocks, 8 groups x 8, monotonic counters
__device__ __forceinline__ void quad_barrier(unsigned* qbar, int lbid, unsigned ep) {
  __syncthreads();   // per-wave vmem drained before s_barrier by compiler
  if (threadIdx.x == 0) {
    asm volatile("s_waitcnt vmcnt(0)" ::: "memory");
    unsigned gslot = (unsigned)(lbid >> 3) * 8u;   // 8 groups, 32B apart
    unsigned tgt = ep * 8u;
    if (__hip_atomic_fetch_add(&qbar[gslot], 1u, __ATOMIC_RELAXED, __HIP_MEMORY_SCOPE_AGENT) == tgt - 1u) {
      if (__hip_atomic_fetch_add(&qbar[64], 1u, __ATOMIC_RELAXED, __HIP_MEMORY_SCOPE_AGENT) == tgt - 1u) {
        __hip_atomic_store(&qbar[72], ep, __ATOMIC_RELAXED, __HIP_MEMORY_SCOPE_AGENT);
      } else {
        while (__hip_atomic_load(&qbar[72], __ATOMIC_RELAXED, __HIP_MEMORY_SCOPE_AGENT) < ep) {}
      }
    } else {
      while (__hip_atomic_load(&qbar[72], __ATOMIC_RELAXED, __HIP_MEMORY_SCOPE_AGENT) < ep) {}
    }
  }
  __syncthreads();
}

// ---- persistent scan: 256 blocks x 256 threads, 4 independent batch-quadrants ----
__global__ __launch_bounds__(256) void scan_kernel(
    const float* __restrict__ Bb, const float* __restrict__ b_x,
    float* __restrict__ ws, float* __restrict__ out)
{
  __shared__ float smem[16384];          // 64 KB state column slice [k][32]

  float* xT  = ws + OFF_XT;
  float* sT  = ws + OFF_ST;
  float* zT  = ws + OFF_ZT;
  float* rsT = ws + OFF_RST;
  float* psT = ws + OFF_PST;
  float* suT = ws + OFF_SUT;
  const float* Wt   = ws + OFF_WT;
  const float* Ut1  = ws + OFF_UT1;
  const float* Ust  = ws + OFF_UST;
  const float* Wxot = ws + OFF_WXOT;
  const __hip_bfloat16* hvT = (const __hip_bfloat16*)(ws + OFF_HV);

  const int tid = threadIdx.x;
  const int bid = blockIdx.x;
  const int q   = bid & 3;           // batch quadrant (fully independent recurrence)
  const int cg  = bid >> 2;          // 0..63 column group = local block id in quadrant
  const int r0  = q * 32;
  const int row = tid & 31;
  const int b   = r0 + row;          // batch row
  const int g   = tid >> 5;          // 0..7

  unsigned* qbar = (unsigned*)ws + q * 128;

  const int c1 = cg * 24 + g * 3;    // phase1: 3 cols
  const int h2 = cg * 8 + g;         // phase2: 1 col
  const int c3 = cg * 16 + g * 2;    // phase3: 2 su cols
  const int xc = cg * 4 + (g & 3);   // phase3: 1 x col (g<4)
  const bool do_x = (g < 4);

  // hoisted per-thread constants
  const float bb0 = Bb[c1 + 0];
  const float bb1 = Bb[c1 + 1];
  const float bb2 = Bb[c1 + 2];
  const float bxv = do_x ? b_x[xc] : 0.0f;

  unsigned ep = 0;

  float hv0 = __bfloat162float(hvT[((size_t)0 * N3 + c1 + 0) * 128 + b]);
  float hv1 = __bfloat162float(hvT[((size_t)0 * N3 + c1 + 1) * 128 + b]);
  float hv2 = __bfloat162float(hvT[((size_t)0 * N3 + c1 + 2) * 128 + b]);

  for (int t = 0; t < TSTEPS; ++t) {
    // ================= Phase 1: gates =================
    {
      // per-thread scalar state prefetch (issued before staging, used after k-loop)
      float suv0 = 0.0f, suv1 = 0.0f, suv2 = 0.0f;
      float sv0  = 0.0f, sv1  = 0.0f, sv2  = 0.0f;
      if (c1 + 0 < 1024) suv0 = ld(suT + (size_t)(c1 + 0) * 128 + b);
      if (c1 + 1 < 1024) suv1 = ld(suT + (size_t)(c1 + 1) * 128 + b);
      if (c1 + 2 < 1024) suv2 = ld(suT + (size_t)(c1 + 2) * 128 + b);
      if (c1 + 0 < 512)  sv0  = ld(sT + (size_t)(c1 + 0) * 128 + b);
      if (c1 + 1 < 512)  sv1  = ld(sT + (size_t)(c1 + 1) * 128 + b);
      if (c1 + 2 < 512)  sv2  = ld(sT + (size_t)(c1 + 2) * 128 + b);

      stage_cols<8192>(xT, r0, tid, smem);   // xT [256][32-slice]
      __syncthreads();

      const float4* B0 = (const float4*)(Wt + (size_t)(c1 + 0) * 256);
      const float4* B1 = (const float4*)(Wt + (size_t)(c1 + 1) * 256);
      const float4* B2 = (const float4*)(Wt + (size_t)(c1 + 2) * 256);
      const float* xl = smem + row;
      float a0 = 0.0f, a1 = 0.0f, a2 = 0.0f;
      #pragma unroll 4
      for (int k4 = 0; k4 < 64; ++k4) {
        float4 w0 = B0[k4], w1 = B1[k4], w2 = B2[k4];
        float x0 = xl[k4 * 128 +  0];
        float x1 = xl[k4 * 128 + 32];
        float x2 = xl[k4 * 128 + 64];
        float x3 = xl[k4 * 128 + 96];
        a0 = fmaf(x0, w0.x, a0); a0 = fmaf(x1, w0.y, a0); a0 = fmaf(x2, w0.z, a0); a0 = fmaf(x3, w0.w, a0);
        a1 = fmaf(x0, w1.x, a1); a1 = fmaf(x1, w1.y, a1); a1 = fmaf(x2, w1.z, a1); a1 = fmaf(x3, w1.w, a1);
        a2 = fmaf(x0, w2.x, a2); a2 = fmaf(x1, w2.y, a2); a2 = fmaf(x2, w2.z, a2); a2 = fmaf(x3, w2.w, a2);
      }
      {
        float pre0 = a0 + hv0 + bb0 + ((c1 + 0 < 1024) ? suv0 : 0.0f);
        float pre1 = a1 + hv1 + bb1 + ((c1 + 1 < 1024) ? suv1 : 0.0f);
        float pre2 = a2 + hv2 + bb2 + ((c1 + 2 < 1024) ? suv2 : 0.0f);
        int c;
        c = c1 + 0;
        if (c < 512)        st(rsT + c * 128 + b, sigmoid_(pre0) * sv0);
        else if (c < 1024)  st(zT + (c - 512) * 128 + b, sigmoid_(pre0));
        else                st(psT + (c - 1024) * 128 + b, pre0);
        c = c1 + 1;
        if (c < 512)        st(rsT + c * 128 + b, sigmoid_(pre1) * sv1);
        else if (c < 1024)  st(zT + (c - 512) * 128 + b, sigmoid_(pre1));
        else                st(psT + (c - 1024) * 128 + b, pre1);
        c = c1 + 2;
        if (c < 512)        st(rsT + c * 128 + b, sigmoid_(pre2) * sv2);
        else if (c < 1024)  st(zT + (c - 512) * 128 + b, sigmoid_(pre2));
        else                st(psT + (c - 1024) * 128 + b, pre2);
      }
    }
    quad_barrier(qbar, cg, ++ep);

    // ================= Phase 2: state update =================
    {
      if (t + 1 < TSTEPS) {
        hv0 = __bfloat162float(hvT[((size_t)(t + 1) * N3 + c1 + 0) * 128 + b]);
        hv1 = __bfloat162float(hvT[((size_t)(t + 1) * N3 + c1 + 1) * 128 + b]);
        hv2 = __bfloat162float(hvT[((size_t)(t + 1) * N3 + c1 + 2) * 128 + b]);
      }
      const int idx = h2 * 128 + b;
      float psv = ld(psT + idx);
      float zv  = ld(zT + idx);
      float sv  = ld(sT + idx);

      stage_cols<16384>(rsT, r0, tid, smem);  // rsT [512][32-slice]
      __syncthreads();

      const float4* Bu = (const float4*)(Ust + (size_t)h2 * 512);
      const float* sl = smem + row;
      float acc = 0.0f;
      #pragma unroll 4
      for (int k4 = 0; k4 < 128; ++k4) {
        float4 w = Bu[k4];
        acc = fmaf(sl[k4 * 128 +  0], w.x, acc);
        acc = fmaf(sl[k4 * 128 + 32], w.y, acc);
        acc = fmaf(sl[k4 * 128 + 64], w.z, acc);
        acc = fmaf(sl[k4 * 128 + 96], w.w, acc);
      }
      float s1 = tanh_(psv + acc);
      st(sT + idx, sv + zv * (s1 - sv));
    }
    quad_barrier(qbar, cg, ++ep);

    // ================= Phase 3: x_out + su lookahead =================
    {
      stage_cols<16384>(sT, r0, tid, smem);   // sT [512][32-slice]
      __syncthreads();

      const float4* Bu0 = (const float4*)(Ut1 + (size_t)(c3 + 0) * 512);
      const float4* Bu1 = (const float4*)(Ut1 + (size_t)(c3 + 1) * 512);
      const float4* Bx  = (const float4*)(Wxot + (size_t)xc * 512);
      const float* sl = smem + row;
      float a0 = 0.0f, a1 = 0.0f, ax = 0.0f;
      #pragma unroll 4
      for (int k4 = 0; k4 < 128; ++k4) {
        float4 w0 = Bu0[k4], w1 = Bu1[k4];
        float s0v = sl[k4 * 128 +  0];
        float s1v = sl[k4 * 128 + 32];
        float s2v = sl[k4 * 128 + 64];
        float s3v = sl[k4 * 128 + 96];
        a0 = fmaf(s0v, w0.x, a0); a0 = fmaf(s1v, w0.y, a0); a0 = fmaf(s2v, w0.z, a0); a0 = fmaf(s3v, w0.w, a0);
        a1 = fmaf(s0v, w1.x, a1); a1 = fmaf(s1v, w1.y, a1); a1 = fmaf(s2v, w1.z, a1); a1 = fmaf(s3v, w1.w, a1);
        if (do_x) {
          float4 wx = Bx[k4];
          ax = fmaf(s0v, wx.x, ax); ax = fmaf(s1v, wx.y, ax); ax = fmaf(s2v, wx.z, ax); ax = fmaf(s3v, wx.w, ax);
        }
      }
      st(suT + (size_t)(c3 + 0) * 128 + b, a0);
      st(suT + (size_t)(c3 + 1) * 128 + b, a1);
      if (do_x) {
        float xv = tanh_(ax + bxv);
        st(xT + xc * 128 + b, xv);
        out[((size_t)b * TSTEPS + t) * ODIM + xc] = xv;
      }
    }
    quad_barrier(qbar, cg, ++ep);
  }
}

extern "C" void kernel_launch(void* const* d_in, const int* in_sizes, int n_in,
                              void* d_out, int out_size, void* d_ws, size_t ws_size,
                              hipStream_t stream) {
  const float* H   = (const float*)d_in[0];
  const float* W   = (const float*)d_in[1];
  const float* Bb  = (const float*)d_in[2];
  const float* U   = (const float*)d_in[3];
  const float* W_x = (const float*)d_in[4];
  const float* b_x = (const float*)d_in[5];
  const float* Vr  = (const float*)d_in[6];
  const float* Vz  = (const float*)d_in[7];
  const float* Vs  = (const float*)d_in[8];
  float* out = (float*)d_out;
  float* ws  = (float*)d_ws;
  __hip_bfloat16* hvT = (__hip_bfloat16*)(ws + OFF_HV);

  prep_kernel<<<5120, 256, 0, stream>>>(W, U, W_x, ws);
  init_kernel<<<512, 256, 0, stream>>>(H, ws);
  hv_kernel<<<dim3(2048, 24), 256, 0, stream>>>(H, Vr, Vz, Vs, hvT);
  scan_kernel<<<256, 256, 0, stream>>>(Bb, b_x, ws, out);
}

// Round 2
// 27128.845 us; speedup vs baseline: 1.5355x; 1.1456x over previous
//
#include <hip/hip_runtime.h>
#include <hip/hip_bf16.h>

#define TSTEPS 512
#define BATCH  128
#define DIM    512
#define HDIM   512
#define ODIM   256
#define N3     1536

// ---- ws layout (float offsets) ----
// Barrier region: 512 uints = 4 independent quadrant barriers at q*128
// (per quadrant: 8 group counters 32B apart at 0..56, root at 64, epoch at 72)
#define OFF_BAR  0
#define OFF_XT   512       // xT  [256][128]
#define OFF_ST   33280     // sT  [512][128]
#define OFF_ZT   98816     // zT  [512][128]
#define OFF_RST  164352    // rsT [512][128]
#define OFF_PST  229888    // psT [512][128]
#define OFF_SUT  295424    // suT [1024][128]
#define OFF_WT   426496    // Wt   [1536][256]
#define OFF_UT1  819712    // Ut1  [1024][512]
#define OFF_UST  1344000   // Ust  [512][512]
#define OFF_WXOT 1606144   // Wxot [256][512]
#define OFF_HV   1737216   // bf16 [512][1536][128]

__device__ __forceinline__ float sigmoid_(float a) {
  return 1.0f / (1.0f + __expf(-a));
}
__device__ __forceinline__ float tanh_(float a) {
  a = fminf(fmaxf(a, -30.0f), 30.0f);
  float e = __expf(2.0f * a);
  return (e - 1.0f) / (e + 1.0f);
}

// LLC-coherent state accessors (sc1 encoding, bypass incoherent per-XCD L2,
// NO fence instructions — weights stay cached in L1/L2).
__device__ __forceinline__ float ld(const float* p) {
  return __hip_atomic_load((float*)p, __ATOMIC_RELAXED, __HIP_MEMORY_SCOPE_AGENT);
}
__device__ __forceinline__ void st(float* p, float v) {
  __hip_atomic_store(p, v, __ATOMIC_RELAXED, __HIP_MEMORY_SCOPE_AGENT);
}

// ---- one-time weight transposes into ws ----
__global__ void prep_kernel(const float* __restrict__ W, const float* __restrict__ U,
                            const float* __restrict__ Wx, float* __restrict__ ws) {
  int i = blockIdx.x * 256 + threadIdx.x;
  if (i < 393216) {                       // Wt[c][k] = W[k][c]
    int c = i >> 8, k = i & 255;
    ws[OFF_WT + i] = W[(size_t)k * N3 + c];
  } else if (i < 917504) {                // Ut1[c][k] = U[k][c], c<1024
    int j = i - 393216; int c = j >> 9, k = j & 511;
    ws[OFF_UT1 + j] = U[(size_t)k * N3 + c];
  } else if (i < 1179648) {               // Ust[c][k] = U[k][1024+c]
    int j = i - 917504; int c = j >> 9, k = j & 511;
    ws[OFF_UST + j] = U[(size_t)k * N3 + 1024 + c];
  } else if (i < 1310720) {               // Wxot[c][k] = W_x[k][c], c<256
    int j = i - 1179648; int c = j >> 9, k = j & 511;
    ws[OFF_WXOT + j] = Wx[(size_t)k * 768 + c];
  }
}

// ---- state init ----
__global__ void init_kernel(const float* __restrict__ H, float* __restrict__ ws) {
  int i = blockIdx.x * 256 + threadIdx.x;   // grid 512 -> 131072
  if (i < 512) ((unsigned*)ws)[OFF_BAR + i] = 0u;
  if (i < 65536) ws[OFF_ST + i] = 0.0f;
  if (i < 131072) ws[OFF_SUT + i] = 0.0f;
  if (i < 32768) {
    int c = i >> 7, b = i & 127;
    const float* hrow = H + ((size_t)b * TSTEPS + (TSTEPS - 1)) * DIM;
    ws[OFF_XT + i] = hrow[c] + hrow[c + ODIM];
  }
}

// ---- hv precompute, transposed bf16 store: hvT[t][c][b] ----
__global__ void hv_kernel(const float* __restrict__ H,
                          const float* __restrict__ Vr,
                          const float* __restrict__ Vz,
                          const float* __restrict__ Vs,
                          __hip_bfloat16* __restrict__ hvT) {
  __shared__ float tile[64 * 33];
  int c  = threadIdx.x & 63;
  int q  = threadIdx.x >> 6;
  int i0 = blockIdx.x * 32;
  int l  = i0 >> 7;
  int b0 = i0 & 127;
  int n0 = blockIdx.y * 64;
  int seg = n0 >> 9;
  int jj  = (n0 & 511) + c;
  const float* V = (seg == 0) ? Vr : ((seg == 1) ? Vz : Vs);

  const float* Arow[8];
  #pragma unroll
  for (int rr = 0; rr < 8; ++rr) {
    int b = b0 + q + rr * 4;
    Arow[rr] = H + ((size_t)b * TSTEPS + (TSTEPS - 1 - l)) * DIM;
  }
  float acc[8];
  #pragma unroll
  for (int rr = 0; rr < 8; ++rr) acc[rr] = 0.0f;

  for (int k = 0; k < DIM; k += 4) {
    float v0 = V[(size_t)(k + 0) * HDIM + jj];
    float v1 = V[(size_t)(k + 1) * HDIM + jj];
    float v2 = V[(size_t)(k + 2) * HDIM + jj];
    float v3 = V[(size_t)(k + 3) * HDIM + jj];
    #pragma unroll
    for (int rr = 0; rr < 8; ++rr) {
      float4 a = *(const float4*)(Arow[rr] + k);
      acc[rr] = fmaf(a.x, v0, acc[rr]);
      acc[rr] = fmaf(a.y, v1, acc[rr]);
      acc[rr] = fmaf(a.z, v2, acc[rr]);
      acc[rr] = fmaf(a.w, v3, acc[rr]);
    }
  }
  #pragma unroll
  for (int rr = 0; rr < 8; ++rr) tile[c * 33 + q + 4 * rr] = acc[rr];
  __syncthreads();
  #pragma unroll
  for (int i = 0; i < 8; ++i) {
    int lin = i * 256 + threadIdx.x;
    int cc = lin >> 5, bb = lin & 31;
    hvT[((size_t)l * N3 + n0 + cc) * 128 + b0 + bb] = __float2bfloat16(tile[cc * 33 + bb]);
  }
}

// ---- cooperative LDS staging of a [ROWS][32] column slice of state[k*128 + r0 + j]
// NT=512 threads. Single batch of PT back-to-back sc1 loads -> ONE LLC round-trip
// per phase (was 4 serialized batches). addr_u = base + u*2048 floats (constant stride).
// Linear layout smem[k*32+j]: staging writes and compute reads both conflict-free.
template<int ELEMS>
__device__ __forceinline__ void stage_cols(const float* __restrict__ src, int r0,
                                           int tid, float* smem) {
  constexpr int PT = ELEMS / 512;        // 16 or 32
  const float* base = src + (size_t)(tid >> 5) * 128 + r0 + (tid & 31);
  float v[PT];
  #pragma unroll
  for (int u = 0; u < PT; ++u) v[u] = ld(base + (size_t)u * 2048);
  float* sb = smem + tid;
  #pragma unroll
  for (int u = 0; u < PT; ++u) sb[u * 512] = v[u];
}

// ---- fence-free quadrant barrier: 64 blocks, 8 groups x 8, monotonic counters
__device__ __forceinline__ void quad_barrier(unsigned* qbar, int lbid, unsigned ep) {
  __syncthreads();   // per-wave vmem drained before s_barrier by compiler
  if (threadIdx.x == 0) {
    asm volatile("s_waitcnt vmcnt(0)" ::: "memory");
    unsigned gslot = (unsigned)(lbid >> 3) * 8u;   // 8 groups, 32B apart
    unsigned tgt = ep * 8u;
    if (__hip_atomic_fetch_add(&qbar[gslot], 1u, __ATOMIC_RELAXED, __HIP_MEMORY_SCOPE_AGENT) == tgt - 1u) {
      if (__hip_atomic_fetch_add(&qbar[64], 1u, __ATOMIC_RELAXED, __HIP_MEMORY_SCOPE_AGENT) == tgt - 1u) {
        __hip_atomic_store(&qbar[72], ep, __ATOMIC_RELAXED, __HIP_MEMORY_SCOPE_AGENT);
      } else {
        while (__hip_atomic_load(&qbar[72], __ATOMIC_RELAXED, __HIP_MEMORY_SCOPE_AGENT) < ep) {}
      }
    } else {
      while (__hip_atomic_load(&qbar[72], __ATOMIC_RELAXED, __HIP_MEMORY_SCOPE_AGENT) < ep) {}
    }
  }
  __syncthreads();
}

// ---- persistent scan: 256 blocks x 512 threads, 4 independent batch-quadrants ----
// 8 waves/block = 2 waves/SIMD (was 1): latency hiding across staging/FMA/barrier.
__global__ __launch_bounds__(512) void scan_kernel(
    const float* __restrict__ Bb, const float* __restrict__ b_x,
    float* __restrict__ ws, float* __restrict__ out)
{
  __shared__ float smem[16384];          // 64 KB state column slice [k][32]

  float* xT  = ws + OFF_XT;
  float* sT  = ws + OFF_ST;
  float* zT  = ws + OFF_ZT;
  float* rsT = ws + OFF_RST;
  float* psT = ws + OFF_PST;
  float* suT = ws + OFF_SUT;
  const float* Wt   = ws + OFF_WT;
  const float* Ut1  = ws + OFF_UT1;
  const float* Ust  = ws + OFF_UST;
  const float* Wxot = ws + OFF_WXOT;
  const __hip_bfloat16* hvT = (const __hip_bfloat16*)(ws + OFF_HV);

  const int tid = threadIdx.x;
  const int bid = blockIdx.x;
  const int q   = bid & 3;           // batch quadrant (independent recurrence)
  const int cg  = bid >> 2;          // 0..63 column group = local block id in quadrant
  const int r0  = q * 32;
  const int row = tid & 31;
  const int b   = r0 + row;          // batch row
  const int g   = tid >> 5;          // 0..15

  unsigned* qbar = (unsigned*)ws + q * 128;

  const bool p1   = (g < 12);
  const int  c1   = cg * 24 + g * 2;     // phase1: 2 cols (c1 even -> pair never straddles 512/1024)
  const bool p2   = (g < 8);
  const int  h2   = cg * 8 + g;          // phase2: 1 col
  const bool dsu  = (g < 8);
  const int  c3   = cg * 16 + g * 2;     // phase3: 2 su cols
  const bool dx   = (g >= 8 && g < 12);
  const int  xc   = cg * 4 + (g - 8);    // phase3: 1 x col

  // hoisted per-thread constants
  const float bb0 = p1 ? Bb[c1 + 0] : 0.0f;
  const float bb1 = p1 ? Bb[c1 + 1] : 0.0f;
  const float bxv = dx ? b_x[xc] : 0.0f;

  unsigned ep = 0;

  float hv0 = 0.0f, hv1 = 0.0f;
  if (p1) {
    hv0 = __bfloat162float(hvT[((size_t)0 * N3 + c1 + 0) * 128 + b]);
    hv1 = __bfloat162float(hvT[((size_t)0 * N3 + c1 + 1) * 128 + b]);
  }

  for (int t = 0; t < TSTEPS; ++t) {
    // ================= Phase 1: gates =================
    {
      // per-thread scalar state prefetch (issued before staging, used after k-loop)
      float suv0 = 0.0f, suv1 = 0.0f, sv0 = 0.0f, sv1 = 0.0f;
      if (p1) {
        if (c1 + 0 < 1024) suv0 = ld(suT + (size_t)(c1 + 0) * 128 + b);
        if (c1 + 1 < 1024) suv1 = ld(suT + (size_t)(c1 + 1) * 128 + b);
        if (c1 + 0 < 512)  sv0  = ld(sT + (size_t)(c1 + 0) * 128 + b);
        if (c1 + 1 < 512)  sv1  = ld(sT + (size_t)(c1 + 1) * 128 + b);
      }

      stage_cols<8192>(xT, r0, tid, smem);   // xT [256][32-slice]
      __syncthreads();

      if (p1) {
        const float4* B0 = (const float4*)(Wt + (size_t)(c1 + 0) * 256);
        const float4* B1 = (const float4*)(Wt + (size_t)(c1 + 1) * 256);
        const float* xl = smem + row;
        float a0 = 0.0f, a1 = 0.0f;
        #pragma unroll 8
        for (int k4 = 0; k4 < 64; ++k4) {
          float4 w0 = B0[k4], w1 = B1[k4];
          float x0 = xl[k4 * 128 +  0];
          float x1 = xl[k4 * 128 + 32];
          float x2 = xl[k4 * 128 + 64];
          float x3 = xl[k4 * 128 + 96];
          a0 = fmaf(x0, w0.x, a0); a0 = fmaf(x1, w0.y, a0); a0 = fmaf(x2, w0.z, a0); a0 = fmaf(x3, w0.w, a0);
          a1 = fmaf(x0, w1.x, a1); a1 = fmaf(x1, w1.y, a1); a1 = fmaf(x2, w1.z, a1); a1 = fmaf(x3, w1.w, a1);
        }
        float pre0 = a0 + hv0 + bb0 + ((c1 + 0 < 1024) ? suv0 : 0.0f);
        float pre1 = a1 + hv1 + bb1 + ((c1 + 1 < 1024) ? suv1 : 0.0f);
        if (c1 < 512) {
          st(rsT + (c1 + 0) * 128 + b, sigmoid_(pre0) * sv0);
          st(rsT + (c1 + 1) * 128 + b, sigmoid_(pre1) * sv1);
        } else if (c1 < 1024) {
          st(zT + (c1 - 512) * 128 + b, sigmoid_(pre0));
          st(zT + (c1 - 511) * 128 + b, sigmoid_(pre1));
        } else {
          st(psT + (c1 - 1024) * 128 + b, pre0);
          st(psT + (c1 - 1023) * 128 + b, pre1);
        }
      }
    }
    quad_barrier(qbar, cg, ++ep);

    // ================= Phase 2: state update =================
    {
      if (p1 && (t + 1 < TSTEPS)) {
        hv0 = __bfloat162float(hvT[((size_t)(t + 1) * N3 + c1 + 0) * 128 + b]);
        hv1 = __bfloat162float(hvT[((size_t)(t + 1) * N3 + c1 + 1) * 128 + b]);
      }
      float psv = 0.0f, zv = 0.0f, sv = 0.0f;
      if (p2) {
        const int idx = h2 * 128 + b;
        psv = ld(psT + idx);
        zv  = ld(zT + idx);
        sv  = ld(sT + idx);
      }

      stage_cols<16384>(rsT, r0, tid, smem);  // rsT [512][32-slice]
      __syncthreads();

      if (p2) {
        const float4* Bu = (const float4*)(Ust + (size_t)h2 * 512);
        const float* sl = smem + row;
        float acc = 0.0f;
        #pragma unroll 8
        for (int k4 = 0; k4 < 128; ++k4) {
          float4 w = Bu[k4];
          acc = fmaf(sl[k4 * 128 +  0], w.x, acc);
          acc = fmaf(sl[k4 * 128 + 32], w.y, acc);
          acc = fmaf(sl[k4 * 128 + 64], w.z, acc);
          acc = fmaf(sl[k4 * 128 + 96], w.w, acc);
        }
        float s1 = tanh_(psv + acc);
        st(sT + h2 * 128 + b, sv + zv * (s1 - sv));
      }
    }
    quad_barrier(qbar, cg, ++ep);

    // ================= Phase 3: x_out + su lookahead =================
    {
      stage_cols<16384>(sT, r0, tid, smem);   // sT [512][32-slice]
      __syncthreads();

      const float* sl = smem + row;
      if (dsu) {
        const float4* Bu0 = (const float4*)(Ut1 + (size_t)(c3 + 0) * 512);
        const float4* Bu1 = (const float4*)(Ut1 + (size_t)(c3 + 1) * 512);
        float a0 = 0.0f, a1 = 0.0f;
        #pragma unroll 8
        for (int k4 = 0; k4 < 128; ++k4) {
          float4 w0 = Bu0[k4], w1 = Bu1[k4];
          float s0v = sl[k4 * 128 +  0];
          float s1v = sl[k4 * 128 + 32];
          float s2v = sl[k4 * 128 + 64];
          float s3v = sl[k4 * 128 + 96];
          a0 = fmaf(s0v, w0.x, a0); a0 = fmaf(s1v, w0.y, a0); a0 = fmaf(s2v, w0.z, a0); a0 = fmaf(s3v, w0.w, a0);
          a1 = fmaf(s0v, w1.x, a1); a1 = fmaf(s1v, w1.y, a1); a1 = fmaf(s2v, w1.z, a1); a1 = fmaf(s3v, w1.w, a1);
        }
        st(suT + (size_t)(c3 + 0) * 128 + b, a0);
        st(suT + (size_t)(c3 + 1) * 128 + b, a1);
      } else if (dx) {
        const float4* Bx = (const float4*)(Wxot + (size_t)xc * 512);
        float ax = 0.0f;
        #pragma unroll 8
        for (int k4 = 0; k4 < 128; ++k4) {
          float4 wx = Bx[k4];
          ax = fmaf(sl[k4 * 128 +  0], wx.x, ax);
          ax = fmaf(sl[k4 * 128 + 32], wx.y, ax);
          ax = fmaf(sl[k4 * 128 + 64], wx.z, ax);
          ax = fmaf(sl[k4 * 128 + 96], wx.w, ax);
        }
        float xv = tanh_(ax + bxv);
        st(xT + xc * 128 + b, xv);
        out[((size_t)b * TSTEPS + t) * ODIM + xc] = xv;
      }
    }
    quad_barrier(qbar, cg, ++ep);
  }
}

extern "C" void kernel_launch(void* const* d_in, const int* in_sizes, int n_in,
                              void* d_out, int out_size, void* d_ws, size_t ws_size,
                              hipStream_t stream) {
  const float* H   = (const float*)d_in[0];
  const float* W   = (const float*)d_in[1];
  const float* Bb  = (const float*)d_in[2];
  const float* U   = (const float*)d_in[3];
  const float* W_x = (const float*)d_in[4];
  const float* b_x = (const float*)d_in[5];
  const float* Vr  = (const float*)d_in[6];
  const float* Vz  = (const float*)d_in[7];
  const float* Vs  = (const float*)d_in[8];
  float* out = (float*)d_out;
  float* ws  = (float*)d_ws;
  __hip_bfloat16* hvT = (__hip_bfloat16*)(ws + OFF_HV);

  prep_kernel<<<5120, 256, 0, stream>>>(W, U, W_x, ws);
  init_kernel<<<512, 256, 0, stream>>>(H, ws);
  hv_kernel<<<dim3(2048, 24), 256, 0, stream>>>(H, Vr, Vz, Vs, hvT);
  scan_kernel<<<256, 512, 0, stream>>>(Bb, b_x, ws, out);
}

// Round 3
// 22831.628 us; speedup vs baseline: 1.8245x; 1.1882x over previous
//
#include <hip/hip_runtime.h>
#include <hip/hip_bf16.h>

#define TSTEPS 512
#define BATCH  128
#define DIM    512
#define HDIM   512
#define ODIM   256
#define N3     1536

// ---- ws layout (float offsets) ----
// Barrier region: 512 uints = 4 independent quadrant barriers at q*128
// (per quadrant: 8 group counters 32B apart at 0..56, root at 64, epoch at 72)
#define OFF_BAR  0
#define OFF_XT   512       // xT  [256][128]
#define OFF_ST   33280     // sT  [512][128]
#define OFF_ZT   98816     // zT  [512][128]
#define OFF_RST  164352    // rsT [512][128]
#define OFF_PST  229888    // psT [512][128]
#define OFF_SUT  295424    // suT [1024][128]
#define OFF_WT   426496    // Wt   [1536][256]
#define OFF_UT1  819712    // Ut1  [1024][512]
#define OFF_UST  1344000   // Ust  [512][512]
#define OFF_WXOT 1606144   // Wxot [256][512]
#define OFF_HV   1737216   // bf16 [512][1536][128]

// Dynamic LDS: [0,16384) state stage; [16384,36864) weights (80KB) = 144KB total
#define LDSF_TOTAL 36864
#define LDS_BYTES  (LDSF_TOTAL * 4)

__device__ __forceinline__ float sigmoid_(float a) {
  return 1.0f / (1.0f + __expf(-a));
}
__device__ __forceinline__ float tanh_(float a) {
  a = fminf(fmaxf(a, -30.0f), 30.0f);
  float e = __expf(2.0f * a);
  return (e - 1.0f) / (e + 1.0f);
}

// LLC-coherent state accessors (sc1 encoding, bypass incoherent per-XCD L2,
// NO fence instructions — weights stay cached in L1/L2/LDS).
__device__ __forceinline__ float ld(const float* p) {
  return __hip_atomic_load((float*)p, __ATOMIC_RELAXED, __HIP_MEMORY_SCOPE_AGENT);
}
__device__ __forceinline__ void st(float* p, float v) {
  __hip_atomic_store(p, v, __ATOMIC_RELAXED, __HIP_MEMORY_SCOPE_AGENT);
}

// Non-temporal bf16 load (keep the 201MB hvT stream from thrashing LLC).
// bf16 -> f32 is an exact shift, identical to __bfloat162float.
__device__ __forceinline__ float ldhv(const __hip_bfloat16* p) {
  unsigned short r = __builtin_nontemporal_load((const unsigned short*)p);
  return __uint_as_float((unsigned)r << 16);
}

// ---- one-time weight transposes into ws ----
__global__ void prep_kernel(const float* __restrict__ W, const float* __restrict__ U,
                            const float* __restrict__ Wx, float* __restrict__ ws) {
  int i = blockIdx.x * 256 + threadIdx.x;
  if (i < 393216) {                       // Wt[c][k] = W[k][c]
    int c = i >> 8, k = i & 255;
    ws[OFF_WT + i] = W[(size_t)k * N3 + c];
  } else if (i < 917504) {                // Ut1[c][k] = U[k][c], c<1024
    int j = i - 393216; int c = j >> 9, k = j & 511;
    ws[OFF_UT1 + j] = U[(size_t)k * N3 + c];
  } else if (i < 1179648) {               // Ust[c][k] = U[k][1024+c]
    int j = i - 917504; int c = j >> 9, k = j & 511;
    ws[OFF_UST + j] = U[(size_t)k * N3 + 1024 + c];
  } else if (i < 1310720) {               // Wxot[c][k] = W_x[k][c], c<256
    int j = i - 1179648; int c = j >> 9, k = j & 511;
    ws[OFF_WXOT + j] = Wx[(size_t)k * 768 + c];
  }
}

// ---- state init ----
__global__ void init_kernel(const float* __restrict__ H, float* __restrict__ ws) {
  int i = blockIdx.x * 256 + threadIdx.x;   // grid 512 -> 131072
  if (i < 512) ((unsigned*)ws)[OFF_BAR + i] = 0u;
  if (i < 65536) ws[OFF_ST + i] = 0.0f;
  if (i < 131072) ws[OFF_SUT + i] = 0.0f;
  if (i < 32768) {
    int c = i >> 7, b = i & 127;
    const float* hrow = H + ((size_t)b * TSTEPS + (TSTEPS - 1)) * DIM;
    ws[OFF_XT + i] = hrow[c] + hrow[c + ODIM];
  }
}

// ---- hv precompute, transposed bf16 store: hvT[t][c][b] ----
__global__ void hv_kernel(const float* __restrict__ H,
                          const float* __restrict__ Vr,
                          const float* __restrict__ Vz,
                          const float* __restrict__ Vs,
                          __hip_bfloat16* __restrict__ hvT) {
  __shared__ float tile[64 * 33];
  int c  = threadIdx.x & 63;
  int q  = threadIdx.x >> 6;
  int i0 = blockIdx.x * 32;
  int l  = i0 >> 7;
  int b0 = i0 & 127;
  int n0 = blockIdx.y * 64;
  int seg = n0 >> 9;
  int jj  = (n0 & 511) + c;
  const float* V = (seg == 0) ? Vr : ((seg == 1) ? Vz : Vs);

  const float* Arow[8];
  #pragma unroll
  for (int rr = 0; rr < 8; ++rr) {
    int b = b0 + q + rr * 4;
    Arow[rr] = H + ((size_t)b * TSTEPS + (TSTEPS - 1 - l)) * DIM;
  }
  float acc[8];
  #pragma unroll
  for (int rr = 0; rr < 8; ++rr) acc[rr] = 0.0f;

  for (int k = 0; k < DIM; k += 4) {
    float v0 = V[(size_t)(k + 0) * HDIM + jj];
    float v1 = V[(size_t)(k + 1) * HDIM + jj];
    float v2 = V[(size_t)(k + 2) * HDIM + jj];
    float v3 = V[(size_t)(k + 3) * HDIM + jj];
    #pragma unroll
    for (int rr = 0; rr < 8; ++rr) {
      float4 a = *(const float4*)(Arow[rr] + k);
      acc[rr] = fmaf(a.x, v0, acc[rr]);
      acc[rr] = fmaf(a.y, v1, acc[rr]);
      acc[rr] = fmaf(a.z, v2, acc[rr]);
      acc[rr] = fmaf(a.w, v3, acc[rr]);
    }
  }
  #pragma unroll
  for (int rr = 0; rr < 8; ++rr) tile[c * 33 + q + 4 * rr] = acc[rr];
  __syncthreads();
  #pragma unroll
  for (int i = 0; i < 8; ++i) {
    int lin = i * 256 + threadIdx.x;
    int cc = lin >> 5, bb = lin & 31;
    __hip_bfloat16 hb = __float2bfloat16(tile[cc * 33 + bb]);
    __builtin_nontemporal_store(*(unsigned short*)&hb,
        (unsigned short*)(hvT + ((size_t)l * N3 + n0 + cc) * 128 + b0 + bb));
  }
}

// ---- cooperative LDS staging of a [ROWS][32] column slice of state[k*128 + r0 + j]
// NT=512 threads. Single batch of PT back-to-back sc1 loads -> ONE LLC round-trip
// per phase. Linear layout smem[k*32+j]: writes and reads both conflict-free.
template<int ELEMS>
__device__ __forceinline__ void stage_cols(const float* __restrict__ src, int r0,
                                           int tid, float* smem) {
  constexpr int PT = ELEMS / 512;        // 16 or 32
  const float* base = src + (size_t)(tid >> 5) * 128 + r0 + (tid & 31);
  float v[PT];
  #pragma unroll
  for (int u = 0; u < PT; ++u) v[u] = ld(base + (size_t)u * 2048);
  float* sb = smem + tid;
  #pragma unroll
  for (int u = 0; u < PT; ++u) sb[u * 512] = v[u];
}

// ---- fence-free quadrant barrier: 64 blocks, 8 groups x 8, monotonic counters
// s_sleep backoff in polls cuts same-line LLC contention from 64 pollers.
__device__ __forceinline__ void quad_barrier(unsigned* qbar, int lbid, unsigned ep) {
  __syncthreads();   // per-wave vmem drained before s_barrier by compiler
  if (threadIdx.x == 0) {
    asm volatile("s_waitcnt vmcnt(0)" ::: "memory");
    unsigned gslot = (unsigned)(lbid >> 3) * 8u;   // 8 groups, 32B apart
    unsigned tgt = ep * 8u;
    if (__hip_atomic_fetch_add(&qbar[gslot], 1u, __ATOMIC_RELAXED, __HIP_MEMORY_SCOPE_AGENT) == tgt - 1u) {
      if (__hip_atomic_fetch_add(&qbar[64], 1u, __ATOMIC_RELAXED, __HIP_MEMORY_SCOPE_AGENT) == tgt - 1u) {
        __hip_atomic_store(&qbar[72], ep, __ATOMIC_RELAXED, __HIP_MEMORY_SCOPE_AGENT);
      } else {
        while (__hip_atomic_load(&qbar[72], __ATOMIC_RELAXED, __HIP_MEMORY_SCOPE_AGENT) < ep) {
          __builtin_amdgcn_s_sleep(1);
        }
      }
    } else {
      while (__hip_atomic_load(&qbar[72], __ATOMIC_RELAXED, __HIP_MEMORY_SCOPE_AGENT) < ep) {
        __builtin_amdgcn_s_sleep(1);
      }
    }
  }
  __syncthreads();
}

// ---- persistent scan: 256 blocks x 512 threads, 4 independent batch-quadrants ----
// Weights (80KB/block, static col ownership) staged into LDS ONCE before the
// t-loop: inner loops read weights via broadcast ds_read (free) instead of
// streaming from LLC (~800cy) every step.
__global__ __launch_bounds__(512) void scan_kernel(
    const float* __restrict__ Bb, const float* __restrict__ b_x,
    float* __restrict__ ws, float* __restrict__ out)
{
  extern __shared__ float smem[];        // [0,16384) stage; [16384,36864) weights

  float* xT  = ws + OFF_XT;
  float* sT  = ws + OFF_ST;
  float* zT  = ws + OFF_ZT;
  float* rsT = ws + OFF_RST;
  float* psT = ws + OFF_PST;
  float* suT = ws + OFF_SUT;
  const float* Wt   = ws + OFF_WT;
  const float* Ut1  = ws + OFF_UT1;
  const float* Ust  = ws + OFF_UST;
  const float* Wxot = ws + OFF_WXOT;
  const __hip_bfloat16* hvT = (const __hip_bfloat16*)(ws + OFF_HV);

  const int tid = threadIdx.x;
  const int bid = blockIdx.x;
  const int q   = bid & 3;           // batch quadrant (independent recurrence)
  const int cg  = bid >> 2;          // 0..63 column group = local block id in quadrant
  const int r0  = q * 32;
  const int row = tid & 31;
  const int b   = r0 + row;          // batch row
  const int g   = tid >> 5;          // 0..15

  unsigned* qbar = (unsigned*)ws + q * 128;

  const bool p1   = (g < 12);
  const int  c1   = cg * 24 + g * 2;     // phase1: 2 cols (even -> pair never straddles 512/1024)
  const bool p2   = (g < 8);
  const int  h2   = cg * 8 + g;          // phase2: 1 col
  const bool dsu  = (g < 8);
  const int  c3   = cg * 16 + g * 2;     // phase3: 2 su cols
  const bool dx   = (g >= 8 && g < 12);
  const int  xc   = cg * 4 + (g - 8);    // phase3: 1 x col

  // ---- one-time weight staging into LDS (cols owned by this block are
  // contiguous in each transposed array) ----
  {
    float4* dst = (float4*)(smem + 16384);
    const float4* sW  = (const float4*)(Wt   + (size_t)cg * 6144);
    const float4* sU2 = (const float4*)(Ust  + (size_t)cg * 4096);
    const float4* sU1 = (const float4*)(Ut1  + (size_t)cg * 8192);
    const float4* sWx = (const float4*)(Wxot + (size_t)cg * 2048);
    #pragma unroll
    for (int u = 0; u < 3; ++u) dst[u * 512 + tid] = sW[u * 512 + tid];
    #pragma unroll
    for (int u = 0; u < 2; ++u) dst[1536 + u * 512 + tid] = sU2[u * 512 + tid];
    #pragma unroll
    for (int u = 0; u < 4; ++u) dst[2560 + u * 512 + tid] = sU1[u * 512 + tid];
    dst[4608 + tid] = sWx[tid];
  }
  const float* wp1  = smem + 16384;          // [24][256]
  const float* wp2  = smem + 16384 + 6144;   // [8][512]
  const float* wp3u = smem + 16384 + 10240;  // [16][512]
  const float* wp3x = smem + 16384 + 18432;  // [4][512]
  __syncthreads();

  // hoisted per-thread constants
  const float bb0 = p1 ? Bb[c1 + 0] : 0.0f;
  const float bb1 = p1 ? Bb[c1 + 1] : 0.0f;
  const float bxv = dx ? b_x[xc] : 0.0f;

  unsigned ep = 0;

  float hv0 = 0.0f, hv1 = 0.0f;
  if (p1) {
    hv0 = ldhv(hvT + ((size_t)0 * N3 + c1 + 0) * 128 + b);
    hv1 = ldhv(hvT + ((size_t)0 * N3 + c1 + 1) * 128 + b);
  }

  for (int t = 0; t < TSTEPS; ++t) {
    // ================= Phase 1: gates =================
    {
      // per-thread scalar state prefetch (issued before staging, used after k-loop)
      float suv0 = 0.0f, suv1 = 0.0f, sv0 = 0.0f, sv1 = 0.0f;
      if (p1) {
        if (c1 + 0 < 1024) suv0 = ld(suT + (size_t)(c1 + 0) * 128 + b);
        if (c1 + 1 < 1024) suv1 = ld(suT + (size_t)(c1 + 1) * 128 + b);
        if (c1 + 0 < 512)  sv0  = ld(sT + (size_t)(c1 + 0) * 128 + b);
        if (c1 + 1 < 512)  sv1  = ld(sT + (size_t)(c1 + 1) * 128 + b);
      }

      stage_cols<8192>(xT, r0, tid, smem);   // xT [256][32-slice]
      __syncthreads();

      if (p1) {
        const float4* B0 = (const float4*)(wp1 + (size_t)(g * 2 + 0) * 256);
        const float4* B1 = (const float4*)(wp1 + (size_t)(g * 2 + 1) * 256);
        const float* xl = smem + row;
        float a0 = 0.0f, a1 = 0.0f;
        #pragma unroll 8
        for (int k4 = 0; k4 < 64; ++k4) {
          float4 w0 = B0[k4], w1 = B1[k4];
          float x0 = xl[k4 * 128 +  0];
          float x1 = xl[k4 * 128 + 32];
          float x2 = xl[k4 * 128 + 64];
          float x3 = xl[k4 * 128 + 96];
          a0 = fmaf(x0, w0.x, a0); a0 = fmaf(x1, w0.y, a0); a0 = fmaf(x2, w0.z, a0); a0 = fmaf(x3, w0.w, a0);
          a1 = fmaf(x0, w1.x, a1); a1 = fmaf(x1, w1.y, a1); a1 = fmaf(x2, w1.z, a1); a1 = fmaf(x3, w1.w, a1);
        }
        float pre0 = a0 + hv0 + bb0 + ((c1 + 0 < 1024) ? suv0 : 0.0f);
        float pre1 = a1 + hv1 + bb1 + ((c1 + 1 < 1024) ? suv1 : 0.0f);
        if (c1 < 512) {
          st(rsT + (c1 + 0) * 128 + b, sigmoid_(pre0) * sv0);
          st(rsT + (c1 + 1) * 128 + b, sigmoid_(pre1) * sv1);
        } else if (c1 < 1024) {
          st(zT + (c1 - 512) * 128 + b, sigmoid_(pre0));
          st(zT + (c1 - 511) * 128 + b, sigmoid_(pre1));
        } else {
          st(psT + (c1 - 1024) * 128 + b, pre0);
          st(psT + (c1 - 1023) * 128 + b, pre1);
        }
      }
    }
    quad_barrier(qbar, cg, ++ep);

    // ================= Phase 2: state update =================
    {
      if (p1 && (t + 1 < TSTEPS)) {
        hv0 = ldhv(hvT + ((size_t)(t + 1) * N3 + c1 + 0) * 128 + b);
        hv1 = ldhv(hvT + ((size_t)(t + 1) * N3 + c1 + 1) * 128 + b);
      }
      float psv = 0.0f, zv = 0.0f, sv = 0.0f;
      if (p2) {
        const int idx = h2 * 128 + b;
        psv = ld(psT + idx);
        zv  = ld(zT + idx);
        sv  = ld(sT + idx);
      }

      stage_cols<16384>(rsT, r0, tid, smem);  // rsT [512][32-slice]
      __syncthreads();

      if (p2) {
        const float4* Bu = (const float4*)(wp2 + (size_t)g * 512);
        const float* sl = smem + row;
        float acc = 0.0f;
        #pragma unroll 8
        for (int k4 = 0; k4 < 128; ++k4) {
          float4 w = Bu[k4];
          acc = fmaf(sl[k4 * 128 +  0], w.x, acc);
          acc = fmaf(sl[k4 * 128 + 32], w.y, acc);
          acc = fmaf(sl[k4 * 128 + 64], w.z, acc);
          acc = fmaf(sl[k4 * 128 + 96], w.w, acc);
        }
        float s1 = tanh_(psv + acc);
        st(sT + h2 * 128 + b, sv + zv * (s1 - sv));
      }
    }
    quad_barrier(qbar, cg, ++ep);

    // ================= Phase 3: x_out + su lookahead =================
    {
      stage_cols<16384>(sT, r0, tid, smem);   // sT [512][32-slice]
      __syncthreads();

      const float* sl = smem + row;
      if (dsu) {
        const float4* Bu0 = (const float4*)(wp3u + (size_t)(g * 2 + 0) * 512);
        const float4* Bu1 = (const float4*)(wp3u + (size_t)(g * 2 + 1) * 512);
        float a0 = 0.0f, a1 = 0.0f;
        #pragma unroll 8
        for (int k4 = 0; k4 < 128; ++k4) {
          float4 w0 = Bu0[k4], w1 = Bu1[k4];
          float s0v = sl[k4 * 128 +  0];
          float s1v = sl[k4 * 128 + 32];
          float s2v = sl[k4 * 128 + 64];
          float s3v = sl[k4 * 128 + 96];
          a0 = fmaf(s0v, w0.x, a0); a0 = fmaf(s1v, w0.y, a0); a0 = fmaf(s2v, w0.z, a0); a0 = fmaf(s3v, w0.w, a0);
          a1 = fmaf(s0v, w1.x, a1); a1 = fmaf(s1v, w1.y, a1); a1 = fmaf(s2v, w1.z, a1); a1 = fmaf(s3v, w1.w, a1);
        }
        st(suT + (size_t)(c3 + 0) * 128 + b, a0);
        st(suT + (size_t)(c3 + 1) * 128 + b, a1);
      } else if (dx) {
        const float4* Bx = (const float4*)(wp3x + (size_t)(g - 8) * 512);
        float ax = 0.0f;
        #pragma unroll 8
        for (int k4 = 0; k4 < 128; ++k4) {
          float4 wx = Bx[k4];
          ax = fmaf(sl[k4 * 128 +  0], wx.x, ax);
          ax = fmaf(sl[k4 * 128 + 32], wx.y, ax);
          ax = fmaf(sl[k4 * 128 + 64], wx.z, ax);
          ax = fmaf(sl[k4 * 128 + 96], wx.w, ax);
        }
        float xv = tanh_(ax + bxv);
        st(xT + xc * 128 + b, xv);
        out[((size_t)b * TSTEPS + t) * ODIM + xc] = xv;
      }
    }
    quad_barrier(qbar, cg, ++ep);
  }
}

extern "C" void kernel_launch(void* const* d_in, const int* in_sizes, int n_in,
                              void* d_out, int out_size, void* d_ws, size_t ws_size,
                              hipStream_t stream) {
  const float* H   = (const float*)d_in[0];
  const float* W   = (const float*)d_in[1];
  const float* Bb  = (const float*)d_in[2];
  const float* U   = (const float*)d_in[3];
  const float* W_x = (const float*)d_in[4];
  const float* b_x = (const float*)d_in[5];
  const float* Vr  = (const float*)d_in[6];
  const float* Vz  = (const float*)d_in[7];
  const float* Vs  = (const float*)d_in[8];
  float* out = (float*)d_out;
  float* ws  = (float*)d_ws;
  __hip_bfloat16* hvT = (__hip_bfloat16*)(ws + OFF_HV);

  hipFuncSetAttribute((const void*)scan_kernel,
                      hipFuncAttributeMaxDynamicSharedMemorySize, LDS_BYTES);

  prep_kernel<<<5120, 256, 0, stream>>>(W, U, W_x, ws);
  init_kernel<<<512, 256, 0, stream>>>(H, ws);
  hv_kernel<<<dim3(2048, 24), 256, 0, stream>>>(H, Vr, Vz, Vs, hvT);
  scan_kernel<<<256, 512, LDS_BYTES, stream>>>(Bb, b_x, ws, out);
}

// Round 4
// 18748.688 us; speedup vs baseline: 2.2218x; 1.2178x over previous
//
#include <hip/hip_runtime.h>
#include <hip/hip_bf16.h>

typedef unsigned long long ull;
typedef unsigned int uint;

#define TSTEPS 512
#define BATCH  128
#define DIM    512
#define HDIM   512
#define ODIM   256
#define N3     1536

// ---- ws layout (float offsets) ----
// Barrier region: 512 uints = 4 independent quadrant barriers at q*128
// (per quadrant: 8 group counters 64B apart at i*16)
#define OFF_BAR  0
#define OFF_XT   512       // xT  [256][128]
#define OFF_ST   33280     // sT  [512][128]
#define OFF_ZT   98816     // zT  [512][128]
#define OFF_RST  164352    // rsT [512][128]
#define OFF_PST  229888    // psT [512][128]
#define OFF_SUT  295424    // suT [1024][128]
#define OFF_WT   426496    // Wt   [1536][256]
#define OFF_UT1  819712    // Ut1  [1024][512]
#define OFF_UST  1344000   // Ust  [512][512]
#define OFF_WXOT 1606144   // Wxot [256][512]
#define OFF_HV   1737216   // bf16 [512][1536][128]

// Dynamic LDS: [0,16384) state stage; [16384,36864) weights (80KB) = 144KB total
#define LDSF_TOTAL 36864
#define LDS_BYTES  (LDSF_TOTAL * 4)

union U64 { ull u; float2 f; double d; };

__device__ __forceinline__ float sigmoid_(float a) {
  return 1.0f / (1.0f + __expf(-a));
}
__device__ __forceinline__ float tanh_(float a) {
  a = fminf(fmaxf(a, -30.0f), 30.0f);
  float e = __expf(2.0f * a);
  return (e - 1.0f) / (e + 1.0f);
}

// LLC-coherent state accessors (sc1 encoding, bypass incoherent per-XCD L2).
__device__ __forceinline__ float ld(const float* p) {
  return __hip_atomic_load((float*)p, __ATOMIC_RELAXED, __HIP_MEMORY_SCOPE_AGENT);
}
__device__ __forceinline__ void st(float* p, float v) {
  __hip_atomic_store(p, v, __ATOMIC_RELAXED, __HIP_MEMORY_SCOPE_AGENT);
}
// 8B coherent accessors (row-pairs are consecutive -> halves instr counts)
__device__ __forceinline__ float2 ld2(const float* p) {
  U64 u; u.u = __hip_atomic_load((ull*)p, __ATOMIC_RELAXED, __HIP_MEMORY_SCOPE_AGENT);
  return u.f;
}
__device__ __forceinline__ void st2(float* p, float2 v) {
  U64 u; u.f = v;
  __hip_atomic_store((ull*)p, u.u, __ATOMIC_RELAXED, __HIP_MEMORY_SCOPE_AGENT);
}

// Non-temporal 4B load of a bf16 row-pair (keeps 201MB hvT stream out of LLC).
__device__ __forceinline__ uint ldhv2(const __hip_bfloat16* p) {
  return __builtin_nontemporal_load((const uint*)p);
}
__device__ __forceinline__ float bflo(uint u) { return __uint_as_float(u << 16); }
__device__ __forceinline__ float bfhi(uint u) { return __uint_as_float(u & 0xffff0000u); }

// ---- one-time weight transposes into ws ----
__global__ void prep_kernel(const float* __restrict__ W, const float* __restrict__ U,
                            const float* __restrict__ Wx, float* __restrict__ ws) {
  int i = blockIdx.x * 256 + threadIdx.x;
  if (i < 393216) {                       // Wt[c][k] = W[k][c]
    int c = i >> 8, k = i & 255;
    ws[OFF_WT + i] = W[(size_t)k * N3 + c];
  } else if (i < 917504) {                // Ut1[c][k] = U[k][c], c<1024
    int j = i - 393216; int c = j >> 9, k = j & 511;
    ws[OFF_UT1 + j] = U[(size_t)k * N3 + c];
  } else if (i < 1179648) {               // Ust[c][k] = U[k][1024+c]
    int j = i - 917504; int c = j >> 9, k = j & 511;
    ws[OFF_UST + j] = U[(size_t)k * N3 + 1024 + c];
  } else if (i < 1310720) {               // Wxot[c][k] = W_x[k][c], c<256
    int j = i - 1179648; int c = j >> 9, k = j & 511;
    ws[OFF_WXOT + j] = Wx[(size_t)k * 768 + c];
  }
}

// ---- state init ----
__global__ void init_kernel(const float* __restrict__ H, float* __restrict__ ws) {
  int i = blockIdx.x * 256 + threadIdx.x;   // grid 512 -> 131072
  if (i < 512) ((unsigned*)ws)[OFF_BAR + i] = 0u;
  if (i < 65536) ws[OFF_ST + i] = 0.0f;
  if (i < 131072) ws[OFF_SUT + i] = 0.0f;
  if (i < 32768) {
    int c = i >> 7, b = i & 127;
    const float* hrow = H + ((size_t)b * TSTEPS + (TSTEPS - 1)) * DIM;
    ws[OFF_XT + i] = hrow[c] + hrow[c + ODIM];
  }
}

// ---- hv precompute, transposed bf16 store: hvT[t][c][b] ----
__global__ void hv_kernel(const float* __restrict__ H,
                          const float* __restrict__ Vr,
                          const float* __restrict__ Vz,
                          const float* __restrict__ Vs,
                          __hip_bfloat16* __restrict__ hvT) {
  __shared__ float tile[64 * 33];
  int c  = threadIdx.x & 63;
  int q  = threadIdx.x >> 6;
  int i0 = blockIdx.x * 32;
  int l  = i0 >> 7;
  int b0 = i0 & 127;
  int n0 = blockIdx.y * 64;
  int seg = n0 >> 9;
  int jj  = (n0 & 511) + c;
  const float* V = (seg == 0) ? Vr : ((seg == 1) ? Vz : Vs);

  const float* Arow[8];
  #pragma unroll
  for (int rr = 0; rr < 8; ++rr) {
    int b = b0 + q + rr * 4;
    Arow[rr] = H + ((size_t)b * TSTEPS + (TSTEPS - 1 - l)) * DIM;
  }
  float acc[8];
  #pragma unroll
  for (int rr = 0; rr < 8; ++rr) acc[rr] = 0.0f;

  for (int k = 0; k < DIM; k += 4) {
    float v0 = V[(size_t)(k + 0) * HDIM + jj];
    float v1 = V[(size_t)(k + 1) * HDIM + jj];
    float v2 = V[(size_t)(k + 2) * HDIM + jj];
    float v3 = V[(size_t)(k + 3) * HDIM + jj];
    #pragma unroll
    for (int rr = 0; rr < 8; ++rr) {
      float4 a = *(const float4*)(Arow[rr] + k);
      acc[rr] = fmaf(a.x, v0, acc[rr]);
      acc[rr] = fmaf(a.y, v1, acc[rr]);
      acc[rr] = fmaf(a.z, v2, acc[rr]);
      acc[rr] = fmaf(a.w, v3, acc[rr]);
    }
  }
  #pragma unroll
  for (int rr = 0; rr < 8; ++rr) tile[c * 33 + q + 4 * rr] = acc[rr];
  __syncthreads();
  #pragma unroll
  for (int i = 0; i < 8; ++i) {
    int lin = i * 256 + threadIdx.x;
    int cc = lin >> 5, bb = lin & 31;
    __hip_bfloat16 hb = __float2bfloat16(tile[cc * 33 + bb]);
    __builtin_nontemporal_store(*(unsigned short*)&hb,
        (unsigned short*)(hvT + ((size_t)l * N3 + n0 + cc) * 128 + b0 + bb));
  }
}

// ---- cooperative LDS staging of a [ROWS][32] column slice, 8B granules ----
// smem layout (as doubles): sd[k*16 + rp] = state{rows 2rp,2rp+1} at col k.
// Loads: 16 lanes x 8B = 128B coalesced; one back-to-back batch -> one LLC RT.
template<int ELEMS>
__device__ __forceinline__ void stage2(const float* __restrict__ src, int r0,
                                       int tid, float* smem) {
  constexpr int PT = ELEMS / 1024;     // doubles per thread: 8 or 16
  const ull* base = (const ull*)(src + r0) + (size_t)(tid >> 4) * 64 + (tid & 15);
  ull v[PT];
  #pragma unroll
  for (int u = 0; u < PT; ++u)
    v[u] = __hip_atomic_load((ull*)(base + (size_t)u * 2048),
                             __ATOMIC_RELAXED, __HIP_MEMORY_SCOPE_AGENT);
  ull* sd = (ull*)smem;
  #pragma unroll
  for (int u = 0; u < PT; ++u) sd[tid + u * 512] = v[u];
}

// ---- 2col x 2row x K-range dot from staged state (b64 reads) ----
__device__ __forceinline__ void dot22(const float* smem, int rp,
                                      const float4* __restrict__ B0,
                                      const float4* __restrict__ B1,
                                      int k04, int nk4,
                                      float& a00, float& a01,
                                      float& a10, float& a11) {
  const ull* sd = (const ull*)smem;
  #pragma unroll 8
  for (int i = 0; i < nk4; ++i) {
    int k4 = k04 + i;
    float4 wa = B0[k4], wb = B1[k4];
    U64 d0, d1, d2, d3;
    d0.u = sd[(k4 * 4 + 0) * 16 + rp];
    d1.u = sd[(k4 * 4 + 1) * 16 + rp];
    d2.u = sd[(k4 * 4 + 2) * 16 + rp];
    d3.u = sd[(k4 * 4 + 3) * 16 + rp];
    a00 = fmaf(d0.f.x, wa.x, a00); a00 = fmaf(d1.f.x, wa.y, a00);
    a00 = fmaf(d2.f.x, wa.z, a00); a00 = fmaf(d3.f.x, wa.w, a00);
    a01 = fmaf(d0.f.y, wa.x, a01); a01 = fmaf(d1.f.y, wa.y, a01);
    a01 = fmaf(d2.f.y, wa.z, a01); a01 = fmaf(d3.f.y, wa.w, a01);
    a10 = fmaf(d0.f.x, wb.x, a10); a10 = fmaf(d1.f.x, wb.y, a10);
    a10 = fmaf(d2.f.x, wb.z, a10); a10 = fmaf(d3.f.x, wb.w, a10);
    a11 = fmaf(d0.f.y, wb.x, a11); a11 = fmaf(d1.f.y, wb.y, a11);
    a11 = fmaf(d2.f.y, wb.z, a11); a11 = fmaf(d3.f.y, wb.w, a11);
  }
}

// ---- flat fence-free quadrant barrier: 8 spread counters, pollers sum all 8.
// Chain = arrival atomic (1 LLC RT) + concurrent 8-load poll detect (1 RT):
// removes the root-atomic + epoch-store hops of the old 2-level tree.
__device__ __forceinline__ void quad_barrier(unsigned* qbar, int lbid, unsigned ep) {
  __syncthreads();   // per-wave vmem drained before s_barrier by compiler
  if (threadIdx.x == 0) {
    asm volatile("s_waitcnt vmcnt(0)" ::: "memory");
    unsigned gslot = (unsigned)(lbid >> 3) * 16u;   // 8 slots, 64B apart
    __hip_atomic_fetch_add(&qbar[gslot], 1u, __ATOMIC_RELAXED, __HIP_MEMORY_SCOPE_AGENT);
    unsigned tgt = ep * 64u;                        // monotone arrival sum
    for (;;) {
      unsigned s = 0;
      #pragma unroll
      for (int i = 0; i < 8; ++i)
        s += __hip_atomic_load(&qbar[i * 16], __ATOMIC_RELAXED, __HIP_MEMORY_SCOPE_AGENT);
      if (s >= tgt) break;
      __builtin_amdgcn_s_sleep(1);
    }
  }
  __syncthreads();
}

// ---- persistent scan: 256 blocks x 512 threads, 4 independent batch-quadrants.
// Fat threads: each computes 2 cols x 2 rows over a K-slice; K-slices live in
// the same wave -> partials combined with shfl_xor (no LDS, no extra sync).
__global__ __launch_bounds__(512) void scan_kernel(
    const float* __restrict__ Bb, const float* __restrict__ b_x,
    float* __restrict__ ws, float* __restrict__ out)
{
  extern __shared__ float smem[];        // [0,16384) stage; [16384,36864) weights

  float* xT  = ws + OFF_XT;
  float* sT  = ws + OFF_ST;
  float* zT  = ws + OFF_ZT;
  float* rsT = ws + OFF_RST;
  float* psT = ws + OFF_PST;
  float* suT = ws + OFF_SUT;
  const float* Wt   = ws + OFF_WT;
  const float* Ut1  = ws + OFF_UT1;
  const float* Ust  = ws + OFF_UST;
  const float* Wxot = ws + OFF_WXOT;
  const __hip_bfloat16* hvT = (const __hip_bfloat16*)(ws + OFF_HV);

  const int tid = threadIdx.x;
  const int bid = blockIdx.x;
  const int q   = bid & 3;           // batch quadrant (independent recurrence)
  const int cg  = bid >> 2;          // 0..63 column group
  const int r0  = q * 32;
  const int rp  = tid & 15;          // row-pair: rows 2rp, 2rp+1
  const int b2  = r0 + rp * 2;       // base batch row of the pair
  const int sub = tid >> 4;          // 0..31

  unsigned* qbar = (unsigned*)ws + q * 128;

  // Phase 1: 24 cols = 12 col-pairs x 2 K-halves(128) -> subs 0..23 (waves 0-5)
  const bool p1   = (sub < 24);
  const int  p1cp = sub >> 1;
  const int  p1kh = sub & 1;          // == tid bit4 -> shfl partner lane^16
  const int  c1   = cg * 24 + p1cp * 2;
  const bool fin1 = p1 && (p1kh == 0);
  // Phase 2: 8 cols = 4 col-pairs x 4 K-quarters(128) -> subs 0..15 (waves 0-3)
  const bool p2   = (sub < 16);
  const int  p2cp = sub >> 2;
  const int  p2kq = sub & 3;          // tid bits 4-5 -> shfl lane^16, lane^32
  const int  h2   = cg * 8 + p2cp * 2;
  const bool fin2 = p2 && (p2kq == 0);
  // Phase 3: 16 su cols = 8 pairs x 2 kh (subs 0..15) + 4 x cols = 2 pairs x 2 kh (subs 16..19, wave 4)
  const bool p3su = (sub < 16);
  const int  p3cp = sub >> 1;
  const int  p3kh = sub & 1;
  const int  c3   = cg * 16 + p3cp * 2;
  const bool p3x  = (sub >= 16 && sub < 20);
  const int  xcp  = (sub - 16) >> 1;
  const int  xkh  = sub & 1;
  const int  xc   = cg * 4 + xcp * 2;
  const bool fin3s = p3su && (p3kh == 0);
  const bool fin3x = p3x && (xkh == 0);

  // ---- one-time weight staging into LDS ----
  {
    float4* dst = (float4*)(smem + 16384);
    const float4* sW  = (const float4*)(Wt   + (size_t)cg * 6144);
    const float4* sU2 = (const float4*)(Ust  + (size_t)cg * 4096);
    const float4* sU1 = (const float4*)(Ut1  + (size_t)cg * 8192);
    const float4* sWx = (const float4*)(Wxot + (size_t)cg * 2048);
    #pragma unroll
    for (int u = 0; u < 3; ++u) dst[u * 512 + tid] = sW[u * 512 + tid];
    #pragma unroll
    for (int u = 0; u < 2; ++u) dst[1536 + u * 512 + tid] = sU2[u * 512 + tid];
    #pragma unroll
    for (int u = 0; u < 4; ++u) dst[2560 + u * 512 + tid] = sU1[u * 512 + tid];
    dst[4608 + tid] = sWx[tid];
  }
  const float* wp1  = smem + 16384;          // [24][256]
  const float* wp2  = smem + 16384 + 6144;   // [8][512]
  const float* wp3u = smem + 16384 + 10240;  // [16][512]
  const float* wp3x = smem + 16384 + 18432;  // [4][512]
  __syncthreads();

  // hoisted per-thread constants
  const float bbv0 = p1 ? Bb[c1 + 0] : 0.0f;
  const float bbv1 = p1 ? Bb[c1 + 1] : 0.0f;
  const float bxv0 = p3x ? b_x[xc + 0] : 0.0f;
  const float bxv1 = p3x ? b_x[xc + 1] : 0.0f;

  unsigned ep = 0;

  float hv00 = 0.f, hv01 = 0.f, hv10 = 0.f, hv11 = 0.f;
  if (fin1) {
    uint u0 = ldhv2(hvT + ((size_t)0 * N3 + c1 + 0) * 128 + b2);
    uint u1 = ldhv2(hvT + ((size_t)0 * N3 + c1 + 1) * 128 + b2);
    hv00 = bflo(u0); hv01 = bfhi(u0); hv10 = bflo(u1); hv11 = bfhi(u1);
  }

  for (int t = 0; t < TSTEPS; ++t) {
    // ================= Phase 1: gates =================
    {
      float2 suv0 = {0.f, 0.f}, suv1 = {0.f, 0.f};
      float2 sv0  = {0.f, 0.f}, sv1  = {0.f, 0.f};
      if (fin1) {
        if (c1 < 1024) {
          suv0 = ld2(suT + (size_t)(c1 + 0) * 128 + b2);
          suv1 = ld2(suT + (size_t)(c1 + 1) * 128 + b2);
        }
        if (c1 < 512) {
          sv0 = ld2(sT + (size_t)(c1 + 0) * 128 + b2);
          sv1 = ld2(sT + (size_t)(c1 + 1) * 128 + b2);
        }
      }
      stage2<8192>(xT, r0, tid, smem);   // xT [256][32-slice]
      __syncthreads();

      if (p1) {
        const float4* B0 = (const float4*)(wp1 + (size_t)(p1cp * 2 + 0) * 256);
        const float4* B1 = (const float4*)(wp1 + (size_t)(p1cp * 2 + 1) * 256);
        float a00 = 0.f, a01 = 0.f, a10 = 0.f, a11 = 0.f;
        dot22(smem, rp, B0, B1, p1kh * 32, 32, a00, a01, a10, a11);
        a00 += __shfl_xor(a00, 16);
        a01 += __shfl_xor(a01, 16);
        a10 += __shfl_xor(a10, 16);
        a11 += __shfl_xor(a11, 16);
        if (fin1) {
          float pre00 = a00 + hv00 + bbv0 + ((c1 < 1024) ? suv0.x : 0.f);
          float pre01 = a01 + hv01 + bbv0 + ((c1 < 1024) ? suv0.y : 0.f);
          float pre10 = a10 + hv10 + bbv1 + ((c1 < 1024) ? suv1.x : 0.f);
          float pre11 = a11 + hv11 + bbv1 + ((c1 < 1024) ? suv1.y : 0.f);
          if (c1 < 512) {
            st2(rsT + (size_t)(c1 + 0) * 128 + b2,
                make_float2(sigmoid_(pre00) * sv0.x, sigmoid_(pre01) * sv0.y));
            st2(rsT + (size_t)(c1 + 1) * 128 + b2,
                make_float2(sigmoid_(pre10) * sv1.x, sigmoid_(pre11) * sv1.y));
          } else if (c1 < 1024) {
            st2(zT + (size_t)(c1 - 512) * 128 + b2,
                make_float2(sigmoid_(pre00), sigmoid_(pre01)));
            st2(zT + (size_t)(c1 - 511) * 128 + b2,
                make_float2(sigmoid_(pre10), sigmoid_(pre11)));
          } else {
            st2(psT + (size_t)(c1 - 1024) * 128 + b2, make_float2(pre00, pre01));
            st2(psT + (size_t)(c1 - 1023) * 128 + b2, make_float2(pre10, pre11));
          }
        }
      }
    }
    quad_barrier(qbar, cg, ++ep);

    // ================= Phase 2: state update =================
    {
      if (fin1 && (t + 1 < TSTEPS)) {
        uint u0 = ldhv2(hvT + ((size_t)(t + 1) * N3 + c1 + 0) * 128 + b2);
        uint u1 = ldhv2(hvT + ((size_t)(t + 1) * N3 + c1 + 1) * 128 + b2);
        hv00 = bflo(u0); hv01 = bfhi(u0); hv10 = bflo(u1); hv11 = bfhi(u1);
      }
      float2 psv0 = {0.f,0.f}, psv1 = {0.f,0.f};
      float2 zv0  = {0.f,0.f}, zv1  = {0.f,0.f};
      float2 sv0  = {0.f,0.f}, sv1  = {0.f,0.f};
      if (fin2) {
        psv0 = ld2(psT + (size_t)(h2 + 0) * 128 + b2);
        psv1 = ld2(psT + (size_t)(h2 + 1) * 128 + b2);
        zv0  = ld2(zT  + (size_t)(h2 + 0) * 128 + b2);
        zv1  = ld2(zT  + (size_t)(h2 + 1) * 128 + b2);
        sv0  = ld2(sT  + (size_t)(h2 + 0) * 128 + b2);
        sv1  = ld2(sT  + (size_t)(h2 + 1) * 128 + b2);
      }
      stage2<16384>(rsT, r0, tid, smem);  // rsT [512][32-slice]
      __syncthreads();

      if (p2) {
        const float4* B0 = (const float4*)(wp2 + (size_t)(p2cp * 2 + 0) * 512);
        const float4* B1 = (const float4*)(wp2 + (size_t)(p2cp * 2 + 1) * 512);
        float a00 = 0.f, a01 = 0.f, a10 = 0.f, a11 = 0.f;
        dot22(smem, rp, B0, B1, p2kq * 32, 32, a00, a01, a10, a11);
        a00 += __shfl_xor(a00, 16); a00 += __shfl_xor(a00, 32);
        a01 += __shfl_xor(a01, 16); a01 += __shfl_xor(a01, 32);
        a10 += __shfl_xor(a10, 16); a10 += __shfl_xor(a10, 32);
        a11 += __shfl_xor(a11, 16); a11 += __shfl_xor(a11, 32);
        if (fin2) {
          float s100 = tanh_(psv0.x + a00);
          float s101 = tanh_(psv0.y + a01);
          float s110 = tanh_(psv1.x + a10);
          float s111 = tanh_(psv1.y + a11);
          st2(sT + (size_t)(h2 + 0) * 128 + b2,
              make_float2(sv0.x + zv0.x * (s100 - sv0.x),
                          sv0.y + zv0.y * (s101 - sv0.y)));
          st2(sT + (size_t)(h2 + 1) * 128 + b2,
              make_float2(sv1.x + zv1.x * (s110 - sv1.x),
                          sv1.y + zv1.y * (s111 - sv1.y)));
        }
      }
    }
    quad_barrier(qbar, cg, ++ep);

    // ================= Phase 3: x_out + su lookahead =================
    {
      stage2<16384>(sT, r0, tid, smem);   // sT [512][32-slice]
      __syncthreads();

      if (p3su) {
        const float4* B0 = (const float4*)(wp3u + (size_t)(p3cp * 2 + 0) * 512);
        const float4* B1 = (const float4*)(wp3u + (size_t)(p3cp * 2 + 1) * 512);
        float a00 = 0.f, a01 = 0.f, a10 = 0.f, a11 = 0.f;
        dot22(smem, rp, B0, B1, p3kh * 64, 64, a00, a01, a10, a11);
        a00 += __shfl_xor(a00, 16);
        a01 += __shfl_xor(a01, 16);
        a10 += __shfl_xor(a10, 16);
        a11 += __shfl_xor(a11, 16);
        if (fin3s) {
          st2(suT + (size_t)(c3 + 0) * 128 + b2, make_float2(a00, a01));
          st2(suT + (size_t)(c3 + 1) * 128 + b2, make_float2(a10, a11));
        }
      } else if (p3x) {
        const float4* B0 = (const float4*)(wp3x + (size_t)(xcp * 2 + 0) * 512);
        const float4* B1 = (const float4*)(wp3x + (size_t)(xcp * 2 + 1) * 512);
        float a00 = 0.f, a01 = 0.f, a10 = 0.f, a11 = 0.f;
        dot22(smem, rp, B0, B1, xkh * 64, 64, a00, a01, a10, a11);
        a00 += __shfl_xor(a00, 16);
        a01 += __shfl_xor(a01, 16);
        a10 += __shfl_xor(a10, 16);
        a11 += __shfl_xor(a11, 16);
        if (fin3x) {
          float xv00 = tanh_(a00 + bxv0);   // col xc,   row b2
          float xv01 = tanh_(a01 + bxv0);   // col xc,   row b2+1
          float xv10 = tanh_(a10 + bxv1);   // col xc+1, row b2
          float xv11 = tanh_(a11 + bxv1);   // col xc+1, row b2+1
          st2(xT + (size_t)(xc + 0) * 128 + b2, make_float2(xv00, xv01));
          st2(xT + (size_t)(xc + 1) * 128 + b2, make_float2(xv10, xv11));
          U64 o0; o0.f = make_float2(xv00, xv10);   // out[b2][t][xc..xc+1]
          U64 o1; o1.f = make_float2(xv01, xv11);   // out[b2+1][t][xc..xc+1]
          __builtin_nontemporal_store(o0.d,
              (double*)(out + ((size_t)(b2 + 0) * TSTEPS + t) * ODIM + xc));
          __builtin_nontemporal_store(o1.d,
              (double*)(out + ((size_t)(b2 + 1) * TSTEPS + t) * ODIM + xc));
        }
      }
    }
    quad_barrier(qbar, cg, ++ep);
  }
}

extern "C" void kernel_launch(void* const* d_in, const int* in_sizes, int n_in,
                              void* d_out, int out_size, void* d_ws, size_t ws_size,
                              hipStream_t stream) {
  const float* H   = (const float*)d_in[0];
  const float* W   = (const float*)d_in[1];
  const float* Bb  = (const float*)d_in[2];
  const float* U   = (const float*)d_in[3];
  const float* W_x = (const float*)d_in[4];
  const float* b_x = (const float*)d_in[5];
  const float* Vr  = (const float*)d_in[6];
  const float* Vz  = (const float*)d_in[7];
  const float* Vs  = (const float*)d_in[8];
  float* out = (float*)d_out;
  float* ws  = (float*)d_ws;
  __hip_bfloat16* hvT = (__hip_bfloat16*)(ws + OFF_HV);

  hipFuncSetAttribute((const void*)scan_kernel,
                      hipFuncAttributeMaxDynamicSharedMemorySize, LDS_BYTES);

  prep_kernel<<<5120, 256, 0, stream>>>(W, U, W_x, ws);
  init_kernel<<<512, 256, 0, stream>>>(H, ws);
  hv_kernel<<<dim3(2048, 24), 256, 0, stream>>>(H, Vr, Vz, Vs, hvT);
  scan_kernel<<<256, 512, LDS_BYTES, stream>>>(Bb, b_x, ws, out);
}